// Round 1
// baseline (953.179 us; speedup 1.0000x reference)
//
#include <hip/hip_runtime.h>
#include <math.h>
#include <stdint.h>

// MoE: B=8192 tokens, D_IN=1024, 8 experts, D_EXP=1024, top-2.
// Sparse pipeline: fp64 gating -> per-expert gathered bf16 MFMA GEMMs.

#define NTOK   8192
#define DIN    1024
#define NEXP   8
#define DEXP   1024
#define MAXROWS 17408   // 16384 assignments + per-expert pad to 128, rounded up
#define MAXTILES 136

typedef __bf16 bf16x8_t __attribute__((ext_vector_type(8)));
typedef float f32x4 __attribute__((ext_vector_type(4)));

__device__ __forceinline__ unsigned short f2bf(float f) {
  union { float f; unsigned int u; } v; v.f = f;
  unsigned int u = v.u;
  u += 0x7fffu + ((u >> 16) & 1u);   // round-to-nearest-even
  return (unsigned short)(u >> 16);
}

__device__ __forceinline__ float bf2f(unsigned short s) {
  union { unsigned int u; float f; } v; v.u = ((unsigned int)s) << 16;
  return v.f;
}

__device__ __forceinline__ void async16(const void* g, void* l) {
  __builtin_amdgcn_global_load_lds((const __attribute__((address_space(1))) void*)g,
                                   (__attribute__((address_space(3))) void*)l, 16, 0, 0);
}

// ---------------- x fp32 -> bf16 ----------------
__global__ __launch_bounds__(256) void convx_kernel(const float* __restrict__ x,
                                                    unsigned short* __restrict__ xbf) {
  int gid = blockIdx.x * 256 + threadIdx.x;          // 8192*1024/4 threads
  float4 v = ((const float4*)x)[gid];
  ushort4 r;
  r.x = f2bf(v.x); r.y = f2bf(v.y); r.z = f2bf(v.z); r.w = f2bf(v.w);
  ((ushort4*)xbf)[gid] = r;
}

// ---------------- w1/w2 fp32 [e][k][n] -> bf16 [e][n][k] (transpose+cast) ----------------
__global__ __launch_bounds__(256) void transw_kernel(const float* __restrict__ w1,
                                                     const float* __restrict__ w2,
                                                     unsigned short* __restrict__ w1T,
                                                     unsigned short* __restrict__ w2T) {
  int bz = blockIdx.z;                                // 0..15: 0-7 -> w1, 8-15 -> w2
  const float* src = (bz < 8) ? w1 : w2;
  unsigned short* dst = (bz < 8) ? w1T : w2T;
  int e = bz & 7;
  int kt = blockIdx.y, nt = blockIdx.x;
  __shared__ float tile[64][65];
  int tid = threadIdx.x;
  int c = tid & 63, r4 = tid >> 6;
  const float* s = src + (size_t)e * DIN * DEXP;
  #pragma unroll
  for (int i = 0; i < 16; ++i) {
    int r = i * 4 + r4;
    tile[r][c] = s[(size_t)(kt * 64 + r) * 1024 + nt * 64 + c];
  }
  __syncthreads();
  unsigned short* d = dst + (size_t)e * DIN * DEXP;
  #pragma unroll
  for (int i = 0; i < 16; ++i) {
    int r = i * 4 + r4;
    d[(size_t)(nt * 64 + r) * 1024 + kt * 64 + c] = f2bf(tile[c][r]);
  }
}

// ---------------- gating: fp64 logits, top-2, softmax ----------------
__global__ __launch_bounds__(256) void gate_kernel(const float* __restrict__ x,
                                                   const float* __restrict__ gw,
                                                   float* __restrict__ outGate,
                                                   int* __restrict__ counts,
                                                   int* __restrict__ topE,
                                                   int* __restrict__ topSlot,
                                                   float* __restrict__ topW) {
  __shared__ float sgwT[NEXP * 1024];                 // [e][k] transposed
  int tid = threadIdx.x;
  for (int i = tid; i < NEXP * 1024; i += 256)
    sgwT[(i & 7) * 1024 + (i >> 3)] = gw[i];          // gw is [k][e]
  __syncthreads();
  int lane = tid & 63, wv = tid >> 6;
  int t = blockIdx.x * 4 + wv;
  double acc[NEXP];
  #pragma unroll
  for (int e = 0; e < NEXP; ++e) acc[e] = 0.0;
  const float* xr = x + (size_t)t * 1024;
  for (int j = 0; j < 16; ++j) {
    int k = j * 64 + lane;
    double xv = (double)xr[k];
    #pragma unroll
    for (int e = 0; e < NEXP; ++e) acc[e] += xv * (double)sgwT[e * 1024 + k];
  }
  #pragma unroll
  for (int off = 32; off > 0; off >>= 1) {
    #pragma unroll
    for (int e = 0; e < NEXP; ++e) acc[e] += __shfl_xor(acc[e], off);
  }
  if (lane == 0) {
    int e0 = 0; double v0 = acc[0];
    #pragma unroll
    for (int e = 1; e < NEXP; ++e) if (acc[e] > v0) { v0 = acc[e]; e0 = e; }
    int e1 = -1; double v1 = -1e300;
    #pragma unroll
    for (int e = 0; e < NEXP; ++e) if (e != e0 && acc[e] > v1) { v1 = acc[e]; e1 = e; }
    float ex = expf((float)(v1 - v0));
    float inv = 1.0f / (1.0f + ex);
    float w0 = inv, w1 = ex * inv;
    outGate[t * 8 + e0] = w0;
    outGate[t * 8 + e1] = w1;
    topE[t * 2 + 0] = e0; topE[t * 2 + 1] = e1;
    topW[t * 2 + 0] = w0; topW[t * 2 + 1] = w1;
    topSlot[t * 2 + 0] = atomicAdd(&counts[e0], 1);
    topSlot[t * 2 + 1] = atomicAdd(&counts[e1], 1);
  }
}

// ---------------- build per-expert padded segments + tile table ----------------
__global__ __launch_bounds__(256) void build_kernel(const int* __restrict__ counts,
                                                    int* __restrict__ offsets,
                                                    int* __restrict__ tileExpert,
                                                    int* __restrict__ tileRowBase,
                                                    int* __restrict__ rowTok,
                                                    float* __restrict__ rowW) {
  int tid = threadIdx.x;
  if (tid == 0) {
    int row = 0, tile = 0;
    for (int e = 0; e < NEXP; ++e) {
      offsets[e] = row;
      int c = counts[e];
      int nt = (c + 127) >> 7;
      for (int i = 0; i < nt; ++i) { tileExpert[tile] = e; tileRowBase[tile] = row + i * 128; ++tile; }
      row += nt << 7;
    }
    for (; tile < MAXTILES; ++tile) tileExpert[tile] = -1;
  }
  for (int i = tid; i < MAXROWS; i += 256) { rowTok[i] = -1; rowW[i] = 0.f; }
}

__global__ __launch_bounds__(256) void scatter_kernel(const int* __restrict__ offsets,
                                                      const int* __restrict__ topE,
                                                      const int* __restrict__ topSlot,
                                                      const float* __restrict__ topW,
                                                      int* __restrict__ rowTok,
                                                      float* __restrict__ rowW) {
  int t = blockIdx.x * 256 + threadIdx.x;
  #pragma unroll
  for (int k = 0; k < 2; ++k) {
    int e = topE[t * 2 + k];
    int g = offsets[e] + topSlot[t * 2 + k];
    rowTok[g] = t;
    rowW[g] = topW[t * 2 + k];
  }
}

// ---------------- GEMM1: h = gelu(Xg @ W1[e] + b1[e]), bf16 out ----------------
__global__ __launch_bounds__(256) void gemm1_kernel(const unsigned short* __restrict__ xbf,
                                                    const unsigned short* __restrict__ w1T,
                                                    const float* __restrict__ b1,
                                                    const int* __restrict__ tileExpert,
                                                    const int* __restrict__ tileRowBase,
                                                    const int* __restrict__ rowTok,
                                                    unsigned short* __restrict__ h) {
  int tileId = blockIdx.y;
  int e = tileExpert[tileId];
  if (e < 0) return;
  int rowBase = tileRowBase[tileId];
  int n0 = blockIdx.x * 128;
  __shared__ __align__(16) unsigned short sm[128 * 64 * 2];  // 32KB: sA | sB
  unsigned short* sA = sm;
  unsigned short* sB = sm + 128 * 64;
  int tid = threadIdx.x, lane = tid & 63;
  int srow = tid >> 3;            // 0..31 (+32 per issue)
  int scol = (tid & 7) * 8;       // k element within BK=64
  int tok[4];
  #pragma unroll
  for (int i = 0; i < 4; ++i) {
    int tk = rowTok[rowBase + srow + i * 32];
    tok[i] = tk < 0 ? 0 : tk;
  }
  const unsigned short* Bmat = w1T + (size_t)e * DIN * DEXP;
  int wm = ((tid >> 6) & 1) * 64, wn = (tid >> 7) * 64;
  int rsel = lane & 15, q8 = (lane >> 4) * 8;
  f32x4 acc[4][4] = {};
  for (int kk = 0; kk < DIN; kk += 64) {
    #pragma unroll
    for (int i = 0; i < 4; ++i) {
      async16(xbf + (size_t)tok[i] * 1024 + kk + scol, sA + (srow + i * 32) * 64 + scol);
      async16(Bmat + (size_t)(n0 + srow + i * 32) * 1024 + kk + scol, sB + (srow + i * 32) * 64 + scol);
    }
    __syncthreads();
    #pragma unroll
    for (int ks = 0; ks < 64; ks += 32) {
      bf16x8_t af[4], bfr[4];
      #pragma unroll
      for (int mi = 0; mi < 4; ++mi)
        af[mi] = *(const bf16x8_t*)&sA[(wm + mi * 16 + rsel) * 64 + ks + q8];
      #pragma unroll
      for (int ni = 0; ni < 4; ++ni)
        bfr[ni] = *(const bf16x8_t*)&sB[(wn + ni * 16 + rsel) * 64 + ks + q8];
      #pragma unroll
      for (int mi = 0; mi < 4; ++mi)
        #pragma unroll
        for (int ni = 0; ni < 4; ++ni)
          acc[mi][ni] = __builtin_amdgcn_mfma_f32_16x16x32_bf16(af[mi], bfr[ni], acc[mi][ni], 0, 0, 0);
    }
    __syncthreads();
  }
  // epilogue: bias + exact gelu -> LDS (bf16, [m][n]) -> coalesced 16B stores
  float b1v[4];
  int quad = lane >> 4;
  #pragma unroll
  for (int ni = 0; ni < 4; ++ni) b1v[ni] = b1[e * 1024 + n0 + wn + ni * 16 + rsel];
  #pragma unroll
  for (int mi = 0; mi < 4; ++mi)
    #pragma unroll
    for (int ni = 0; ni < 4; ++ni)
      #pragma unroll
      for (int r = 0; r < 4; ++r) {
        int m = wm + mi * 16 + quad * 4 + r;
        int n = wn + ni * 16 + rsel;
        float v = acc[mi][ni][r] + b1v[ni];
        v = 0.5f * v * (1.0f + erff(v * 0.70710678118654752f));
        sm[m * 128 + n] = f2bf(v);
      }
  __syncthreads();
  #pragma unroll
  for (int i = 0; i < 8; ++i) {
    int idx = i * 2048 + tid * 8;
    int m = idx >> 7, c = idx & 127;
    int g = rowBase + m;
    *(uint4*)(h + (size_t)g * 1024 + n0 + c) = *(const uint4*)&sm[idx];
  }
}

// ---------------- GEMM2: out[tok] += w * (h @ W2[e] + b2[e]) ----------------
__global__ __launch_bounds__(256) void gemm2_kernel(const unsigned short* __restrict__ h,
                                                    const unsigned short* __restrict__ w2T,
                                                    const float* __restrict__ b2,
                                                    const int* __restrict__ tileExpert,
                                                    const int* __restrict__ tileRowBase,
                                                    const int* __restrict__ rowTok,
                                                    const float* __restrict__ rowW,
                                                    float* __restrict__ out) {
  int tileId = blockIdx.y;
  int e = tileExpert[tileId];
  if (e < 0) return;
  int rowBase = tileRowBase[tileId];
  int n0 = blockIdx.x * 128;
  __shared__ __align__(16) unsigned short sm[128 * 64 * 2];
  unsigned short* sA = sm;
  unsigned short* sB = sm + 128 * 64;
  int tid = threadIdx.x, lane = tid & 63;
  int srow = tid >> 3;
  int scol = (tid & 7) * 8;
  const unsigned short* Bmat = w2T + (size_t)e * DEXP * DEXP;
  int wm = ((tid >> 6) & 1) * 64, wn = (tid >> 7) * 64;
  int rsel = lane & 15, q8 = (lane >> 4) * 8;
  f32x4 acc[4][4] = {};
  for (int kk = 0; kk < DEXP; kk += 64) {
    #pragma unroll
    for (int i = 0; i < 4; ++i) {
      async16(h + (size_t)(rowBase + srow + i * 32) * 1024 + kk + scol, sA + (srow + i * 32) * 64 + scol);
      async16(Bmat + (size_t)(n0 + srow + i * 32) * 1024 + kk + scol, sB + (srow + i * 32) * 64 + scol);
    }
    __syncthreads();
    #pragma unroll
    for (int ks = 0; ks < 64; ks += 32) {
      bf16x8_t af[4], bfr[4];
      #pragma unroll
      for (int mi = 0; mi < 4; ++mi)
        af[mi] = *(const bf16x8_t*)&sA[(wm + mi * 16 + rsel) * 64 + ks + q8];
      #pragma unroll
      for (int ni = 0; ni < 4; ++ni)
        bfr[ni] = *(const bf16x8_t*)&sB[(wn + ni * 16 + rsel) * 64 + ks + q8];
      #pragma unroll
      for (int mi = 0; mi < 4; ++mi)
        #pragma unroll
        for (int ni = 0; ni < 4; ++ni)
          acc[mi][ni] = __builtin_amdgcn_mfma_f32_16x16x32_bf16(af[mi], bfr[ni], acc[mi][ni], 0, 0, 0);
    }
    __syncthreads();
  }
  // epilogue: bias -> LDS bf16, then weighted fp32 atomicAdd into out
  float b2v[4];
  int quad = lane >> 4;
  #pragma unroll
  for (int ni = 0; ni < 4; ++ni) b2v[ni] = b2[e * 1024 + n0 + wn + ni * 16 + rsel];
  #pragma unroll
  for (int mi = 0; mi < 4; ++mi)
    #pragma unroll
    for (int ni = 0; ni < 4; ++ni)
      #pragma unroll
      for (int r = 0; r < 4; ++r) {
        int m = wm + mi * 16 + quad * 4 + r;
        int n = wn + ni * 16 + rsel;
        sm[m * 128 + n] = f2bf(acc[mi][ni][r] + b2v[ni]);
      }
  __syncthreads();
  #pragma unroll
  for (int i = 0; i < 8; ++i) {
    int idx = i * 2048 + tid * 8;
    int m = idx >> 7, c = idx & 127;
    int g = rowBase + m;
    int tk = rowTok[g];
    if (tk >= 0) {
      float w = rowW[g];
      float* op = out + (size_t)tk * 1024 + n0 + c;
      #pragma unroll
      for (int j = 0; j < 8; ++j)
        atomicAdd(op + j, w * bf2f(sm[idx + j]));
    }
  }
}

extern "C" void kernel_launch(void* const* d_in, const int* in_sizes, int n_in,
                              void* d_out, int out_size, void* d_ws, size_t ws_size,
                              hipStream_t stream) {
  const float* x  = (const float*)d_in[0];
  const float* gw = (const float*)d_in[1];
  const float* w1 = (const float*)d_in[2];
  const float* b1 = (const float*)d_in[3];
  const float* w2 = (const float*)d_in[4];
  const float* b2 = (const float*)d_in[5];
  float* out = (float*)d_out;

  char* ws = (char*)d_ws;
  int* counts      = (int*)ws;                 // 8
  int* offsets     = counts + 8;               // 8
  int* tileExpert  = counts + 16;              // 136
  int* tileRowBase = counts + 16 + MAXTILES;   // 136
  int* topE        = counts + 16 + 2 * MAXTILES;          // 16384
  int* topSlot     = topE + 16384;                        // 16384
  int* rowTok      = topSlot + 16384;                     // 17408
  float* topW      = (float*)(rowTok + MAXROWS);          // 16384
  float* rowW      = topW + 16384;                        // 17408
  unsigned short* xbf  = (unsigned short*)(ws + (512 << 10));
  unsigned short* w1T  = xbf + (size_t)NTOK * DIN;
  unsigned short* w2T  = w1T + (size_t)NEXP * DIN * DEXP;
  unsigned short* hbuf = w2T + (size_t)NEXP * DEXP * DEXP;
  // total ws use: 512KB + 16MB + 16MB + 16MB + ~34MB ≈ 83MB

  hipMemsetAsync(d_out, 0, (size_t)out_size * sizeof(float), stream);
  hipMemsetAsync(counts, 0, NEXP * sizeof(int), stream);

  convx_kernel<<<(NTOK * DIN / 4) / 256, 256, 0, stream>>>(x, xbf);
  transw_kernel<<<dim3(16, 16, 16), 256, 0, stream>>>(w1, w2, w1T, w2T);
  gate_kernel<<<NTOK / 4, 256, 0, stream>>>(x, gw, out + (size_t)NTOK * DEXP,
                                            counts, topE, topSlot, topW);
  build_kernel<<<1, 256, 0, stream>>>(counts, offsets, tileExpert, tileRowBase, rowTok, rowW);
  scatter_kernel<<<NTOK / 256, 256, 0, stream>>>(offsets, topE, topSlot, topW, rowTok, rowW);
  gemm1_kernel<<<dim3(8, MAXTILES), 256, 0, stream>>>(xbf, w1T, b1, tileExpert, tileRowBase,
                                                      rowTok, hbuf);
  gemm2_kernel<<<dim3(8, MAXTILES), 256, 0, stream>>>(hbuf, w2T, b2, tileExpert, tileRowBase,
                                                      rowTok, rowW, out);
}

// Round 2
// 523.718 us; speedup vs baseline: 1.8200x; 1.8200x over previous
//
#include <hip/hip_runtime.h>
#include <math.h>
#include <stdint.h>

// MoE: B=8192 tokens, D_IN=1024, 8 experts, D_EXP=1024, top-2.
// Sparse pipeline: fp64 gating -> per-expert gathered bf16 MFMA GEMMs ->
// per-row y buffer -> coalesced weighted combine (no atomics).

#define NTOK   8192
#define DIN    1024
#define NEXP   8
#define DEXP   1024
#define MAXROWS 17408   // 16384 assignments + per-expert pad to 128, rounded up
#define MAXTILES 136

typedef __bf16 bf16x8_t __attribute__((ext_vector_type(8)));
typedef float f32x4 __attribute__((ext_vector_type(4)));

__device__ __forceinline__ unsigned short f2bf(float f) {
  union { float f; unsigned int u; } v; v.f = f;
  unsigned int u = v.u;
  u += 0x7fffu + ((u >> 16) & 1u);   // round-to-nearest-even
  return (unsigned short)(u >> 16);
}

__device__ __forceinline__ float bf2f(unsigned short s) {
  union { unsigned int u; float f; } v; v.u = ((unsigned int)s) << 16;
  return v.f;
}

__device__ __forceinline__ void async16(const void* g, void* l) {
  __builtin_amdgcn_global_load_lds((const __attribute__((address_space(1))) void*)g,
                                   (__attribute__((address_space(3))) void*)l, 16, 0, 0);
}

// ---------------- x fp32 -> bf16 ----------------
__global__ __launch_bounds__(256) void convx_kernel(const float* __restrict__ x,
                                                    unsigned short* __restrict__ xbf) {
  int gid = blockIdx.x * 256 + threadIdx.x;
  float4 v = ((const float4*)x)[gid];
  ushort4 r;
  r.x = f2bf(v.x); r.y = f2bf(v.y); r.z = f2bf(v.z); r.w = f2bf(v.w);
  ((ushort4*)xbf)[gid] = r;
}

// ---------------- w1/w2 fp32 [e][k][n] -> bf16 [e][n][k] (transpose+cast) ----------------
__global__ __launch_bounds__(256) void transw_kernel(const float* __restrict__ w1,
                                                     const float* __restrict__ w2,
                                                     unsigned short* __restrict__ w1T,
                                                     unsigned short* __restrict__ w2T) {
  int bz = blockIdx.z;                                // 0..15: 0-7 -> w1, 8-15 -> w2
  const float* src = (bz < 8) ? w1 : w2;
  unsigned short* dst = (bz < 8) ? w1T : w2T;
  int e = bz & 7;
  int kt = blockIdx.y, nt = blockIdx.x;
  __shared__ float tile[64][65];
  int tid = threadIdx.x;
  int c = tid & 63, r4 = tid >> 6;
  const float* s = src + (size_t)e * DIN * DEXP;
  #pragma unroll
  for (int i = 0; i < 16; ++i) {
    int r = i * 4 + r4;
    tile[r][c] = s[(size_t)(kt * 64 + r) * 1024 + nt * 64 + c];
  }
  __syncthreads();
  unsigned short* d = dst + (size_t)e * DIN * DEXP;
  #pragma unroll
  for (int i = 0; i < 16; ++i) {
    int r = i * 4 + r4;
    d[(size_t)(nt * 64 + r) * 1024 + kt * 64 + c] = f2bf(tile[c][r]);
  }
}

// ---------------- gating: fp64 logits, top-2, softmax ----------------
__global__ __launch_bounds__(256) void gate_kernel(const float* __restrict__ x,
                                                   const float* __restrict__ gw,
                                                   float* __restrict__ outGate,
                                                   int* __restrict__ counts,
                                                   int* __restrict__ topE,
                                                   int* __restrict__ topSlot,
                                                   float* __restrict__ topW) {
  __shared__ float sgwT[NEXP * 1024];                 // [e][k] transposed
  int tid = threadIdx.x;
  for (int i = tid; i < NEXP * 1024; i += 256)
    sgwT[(i & 7) * 1024 + (i >> 3)] = gw[i];          // gw is [k][e]
  __syncthreads();
  int lane = tid & 63, wv = tid >> 6;
  int t = blockIdx.x * 4 + wv;
  double acc[NEXP];
  #pragma unroll
  for (int e = 0; e < NEXP; ++e) acc[e] = 0.0;
  const float* xr = x + (size_t)t * 1024;
  for (int j = 0; j < 16; ++j) {
    int k = j * 64 + lane;
    double xv = (double)xr[k];
    #pragma unroll
    for (int e = 0; e < NEXP; ++e) acc[e] += xv * (double)sgwT[e * 1024 + k];
  }
  #pragma unroll
  for (int off = 32; off > 0; off >>= 1) {
    #pragma unroll
    for (int e = 0; e < NEXP; ++e) acc[e] += __shfl_xor(acc[e], off);
  }
  if (lane == 0) {
    int e0 = 0; double v0 = acc[0];
    #pragma unroll
    for (int e = 1; e < NEXP; ++e) if (acc[e] > v0) { v0 = acc[e]; e0 = e; }
    int e1 = -1; double v1 = -1e300;
    #pragma unroll
    for (int e = 0; e < NEXP; ++e) if (e != e0 && acc[e] > v1) { v1 = acc[e]; e1 = e; }
    float ex = expf((float)(v1 - v0));
    float inv = 1.0f / (1.0f + ex);
    float w0 = inv, w1 = ex * inv;
    float g8[8];
    #pragma unroll
    for (int e = 0; e < NEXP; ++e) g8[e] = 0.f;
    g8[e0] = w0; g8[e1] = w1;
    float4* gp = (float4*)(outGate + t * 8);
    gp[0] = *(float4*)&g8[0];
    gp[1] = *(float4*)&g8[4];
    topE[t * 2 + 0] = e0; topE[t * 2 + 1] = e1;
    topW[t * 2 + 0] = w0; topW[t * 2 + 1] = w1;
    topSlot[t * 2 + 0] = atomicAdd(&counts[e0], 1);
    topSlot[t * 2 + 1] = atomicAdd(&counts[e1], 1);
  }
}

// ---------------- build per-expert padded segments + tile table ----------------
__global__ __launch_bounds__(256) void build_kernel(const int* __restrict__ counts,
                                                    int* __restrict__ offsets,
                                                    int* __restrict__ tileExpert,
                                                    int* __restrict__ tileRowBase,
                                                    int* __restrict__ rowTok) {
  int tid = threadIdx.x;
  if (tid == 0) {
    int row = 0, tile = 0;
    for (int e = 0; e < NEXP; ++e) {
      offsets[e] = row;
      int c = counts[e];
      int nt = (c + 127) >> 7;
      for (int i = 0; i < nt; ++i) { tileExpert[tile] = e; tileRowBase[tile] = row + i * 128; ++tile; }
      row += nt << 7;
    }
    for (; tile < MAXTILES; ++tile) tileExpert[tile] = -1;
  }
  for (int i = tid; i < MAXROWS; i += 256) rowTok[i] = -1;
}

__global__ __launch_bounds__(256) void scatter_kernel(const int* __restrict__ offsets,
                                                      const int* __restrict__ topE,
                                                      const int* __restrict__ topSlot,
                                                      int* __restrict__ rowTok) {
  int t = blockIdx.x * 256 + threadIdx.x;
  #pragma unroll
  for (int k = 0; k < 2; ++k) {
    int e = topE[t * 2 + k];
    int g = offsets[e] + topSlot[t * 2 + k];
    rowTok[g] = t;
  }
}

// ---------------- GEMM1: h = gelu(Xg @ W1[e] + b1[e]), bf16 out ----------------
__global__ __launch_bounds__(256) void gemm1_kernel(const unsigned short* __restrict__ xbf,
                                                    const unsigned short* __restrict__ w1T,
                                                    const float* __restrict__ b1,
                                                    const int* __restrict__ tileExpert,
                                                    const int* __restrict__ tileRowBase,
                                                    const int* __restrict__ rowTok,
                                                    unsigned short* __restrict__ h) {
  int tileId = blockIdx.y;
  int e = tileExpert[tileId];
  if (e < 0) return;
  int rowBase = tileRowBase[tileId];
  int n0 = blockIdx.x * 128;
  __shared__ __align__(16) unsigned short sm[128 * 64 * 2];  // 32KB: sA | sB
  unsigned short* sA = sm;
  unsigned short* sB = sm + 128 * 64;
  int tid = threadIdx.x, lane = tid & 63, wv = tid >> 6;
  int srow = tid >> 3;            // 0..31 (+32 per issue)
  int scol = (tid & 7) * 8;       // k element within BK=64
  int tok[4];
  #pragma unroll
  for (int i = 0; i < 4; ++i) {
    int tk = rowTok[rowBase + srow + i * 32];
    tok[i] = tk < 0 ? 0 : tk;
  }
  const unsigned short* Bmat = w1T + (size_t)e * DIN * DEXP;
  int wm = ((tid >> 6) & 1) * 64, wn = (tid >> 7) * 64;
  int rsel = lane & 15, q8 = (lane >> 4) * 8;
  f32x4 acc[4][4] = {};
  for (int kk = 0; kk < DIN; kk += 64) {
    #pragma unroll
    for (int i = 0; i < 4; ++i) {
      // wave-uniform LDS byte base: lane l lands at base + l*16 (HW rule)
      int abase = __builtin_amdgcn_readfirstlane((wv * 8 + i * 32) * 128);
      async16(xbf + (size_t)tok[i] * 1024 + kk + scol, (char*)sm + abase);
      async16(Bmat + (size_t)(n0 + srow + i * 32) * 1024 + kk + scol,
              (char*)sm + abase + 16384);
    }
    __syncthreads();
    #pragma unroll
    for (int ks = 0; ks < 64; ks += 32) {
      bf16x8_t af[4], bfr[4];
      #pragma unroll
      for (int mi = 0; mi < 4; ++mi)
        af[mi] = *(const bf16x8_t*)&sA[(wm + mi * 16 + rsel) * 64 + ks + q8];
      #pragma unroll
      for (int ni = 0; ni < 4; ++ni)
        bfr[ni] = *(const bf16x8_t*)&sB[(wn + ni * 16 + rsel) * 64 + ks + q8];
      #pragma unroll
      for (int mi = 0; mi < 4; ++mi)
        #pragma unroll
        for (int ni = 0; ni < 4; ++ni)
          acc[mi][ni] = __builtin_amdgcn_mfma_f32_16x16x32_bf16(af[mi], bfr[ni], acc[mi][ni], 0, 0, 0);
    }
    __syncthreads();
  }
  // epilogue: bias + exact gelu -> LDS (bf16, [m][n]) -> coalesced 16B stores
  float b1v[4];
  int quad = lane >> 4;
  #pragma unroll
  for (int ni = 0; ni < 4; ++ni) b1v[ni] = b1[e * 1024 + n0 + wn + ni * 16 + rsel];
  #pragma unroll
  for (int mi = 0; mi < 4; ++mi)
    #pragma unroll
    for (int ni = 0; ni < 4; ++ni)
      #pragma unroll
      for (int r = 0; r < 4; ++r) {
        int m = wm + mi * 16 + quad * 4 + r;
        int n = wn + ni * 16 + rsel;
        float v = acc[mi][ni][r] + b1v[ni];
        v = 0.5f * v * (1.0f + erff(v * 0.70710678118654752f));
        sm[m * 128 + n] = f2bf(v);
      }
  __syncthreads();
  #pragma unroll
  for (int i = 0; i < 8; ++i) {
    int idx = i * 2048 + tid * 8;
    int m = idx >> 7, c = idx & 127;
    int g = rowBase + m;
    *(uint4*)(h + (size_t)g * 1024 + n0 + c) = *(const uint4*)&sm[idx];
  }
}

// ---------------- GEMM2: y[row] = h[row] @ W2[e] + b2[e] (bf16, no atomics) ----------------
__global__ __launch_bounds__(256) void gemm2_kernel(const unsigned short* __restrict__ h,
                                                    const unsigned short* __restrict__ w2T,
                                                    const float* __restrict__ b2,
                                                    const int* __restrict__ tileExpert,
                                                    const int* __restrict__ tileRowBase,
                                                    unsigned short* __restrict__ y) {
  int tileId = blockIdx.y;
  int e = tileExpert[tileId];
  if (e < 0) return;
  int rowBase = tileRowBase[tileId];
  int n0 = blockIdx.x * 128;
  __shared__ __align__(16) unsigned short sm[128 * 64 * 2];
  unsigned short* sA = sm;
  unsigned short* sB = sm + 128 * 64;
  int tid = threadIdx.x, lane = tid & 63, wv = tid >> 6;
  int srow = tid >> 3;
  int scol = (tid & 7) * 8;
  const unsigned short* Bmat = w2T + (size_t)e * DEXP * DEXP;
  int wm = ((tid >> 6) & 1) * 64, wn = (tid >> 7) * 64;
  int rsel = lane & 15, q8 = (lane >> 4) * 8;
  f32x4 acc[4][4] = {};
  for (int kk = 0; kk < DEXP; kk += 64) {
    #pragma unroll
    for (int i = 0; i < 4; ++i) {
      int abase = __builtin_amdgcn_readfirstlane((wv * 8 + i * 32) * 128);
      async16(h + (size_t)(rowBase + srow + i * 32) * 1024 + kk + scol, (char*)sm + abase);
      async16(Bmat + (size_t)(n0 + srow + i * 32) * 1024 + kk + scol,
              (char*)sm + abase + 16384);
    }
    __syncthreads();
    #pragma unroll
    for (int ks = 0; ks < 64; ks += 32) {
      bf16x8_t af[4], bfr[4];
      #pragma unroll
      for (int mi = 0; mi < 4; ++mi)
        af[mi] = *(const bf16x8_t*)&sA[(wm + mi * 16 + rsel) * 64 + ks + q8];
      #pragma unroll
      for (int ni = 0; ni < 4; ++ni)
        bfr[ni] = *(const bf16x8_t*)&sB[(wn + ni * 16 + rsel) * 64 + ks + q8];
      #pragma unroll
      for (int mi = 0; mi < 4; ++mi)
        #pragma unroll
        for (int ni = 0; ni < 4; ++ni)
          acc[mi][ni] = __builtin_amdgcn_mfma_f32_16x16x32_bf16(af[mi], bfr[ni], acc[mi][ni], 0, 0, 0);
    }
    __syncthreads();
  }
  // epilogue: bias -> LDS bf16 -> coalesced 16B stores into y
  float b2v[4];
  int quad = lane >> 4;
  #pragma unroll
  for (int ni = 0; ni < 4; ++ni) b2v[ni] = b2[e * 1024 + n0 + wn + ni * 16 + rsel];
  #pragma unroll
  for (int mi = 0; mi < 4; ++mi)
    #pragma unroll
    for (int ni = 0; ni < 4; ++ni)
      #pragma unroll
      for (int r = 0; r < 4; ++r) {
        int m = wm + mi * 16 + quad * 4 + r;
        int n = wn + ni * 16 + rsel;
        sm[m * 128 + n] = f2bf(acc[mi][ni][r] + b2v[ni]);
      }
  __syncthreads();
  #pragma unroll
  for (int i = 0; i < 8; ++i) {
    int idx = i * 2048 + tid * 8;
    int m = idx >> 7, c = idx & 127;
    int g = rowBase + m;
    *(uint4*)(y + (size_t)g * 1024 + n0 + c) = *(const uint4*)&sm[idx];
  }
}

// ---------------- combine: out[t] = w0*y[r0] + w1*y[r1] ----------------
__global__ __launch_bounds__(256) void combine_kernel(const unsigned short* __restrict__ y,
                                                      const int* __restrict__ offsets,
                                                      const int* __restrict__ topE,
                                                      const int* __restrict__ topSlot,
                                                      const float* __restrict__ topW,
                                                      float* __restrict__ out) {
  int tid = threadIdx.x;
  int wv = tid >> 6, lane = tid & 63;
  int t = blockIdx.x * 4 + wv;
  int e0 = topE[t * 2 + 0], e1 = topE[t * 2 + 1];
  int r0 = offsets[e0] + topSlot[t * 2 + 0];
  int r1 = offsets[e1] + topSlot[t * 2 + 1];
  float w0 = topW[t * 2 + 0], w1 = topW[t * 2 + 1];
  const unsigned short* p0 = y + (size_t)r0 * 1024 + lane * 16;
  const unsigned short* p1 = y + (size_t)r1 * 1024 + lane * 16;
  float* op = out + (size_t)t * 1024 + lane * 16;
  #pragma unroll
  for (int hh = 0; hh < 2; ++hh) {
    union { uint4 v; unsigned short s[8]; } a, b;
    a.v = *(const uint4*)(p0 + hh * 8);
    b.v = *(const uint4*)(p1 + hh * 8);
    float o[8];
    #pragma unroll
    for (int j = 0; j < 8; ++j)
      o[j] = w0 * bf2f(a.s[j]) + w1 * bf2f(b.s[j]);
    *(float4*)(op + hh * 8) = *(float4*)&o[0];
    *(float4*)(op + hh * 8 + 4) = *(float4*)&o[4];
  }
}

extern "C" void kernel_launch(void* const* d_in, const int* in_sizes, int n_in,
                              void* d_out, int out_size, void* d_ws, size_t ws_size,
                              hipStream_t stream) {
  const float* x  = (const float*)d_in[0];
  const float* gw = (const float*)d_in[1];
  const float* w1 = (const float*)d_in[2];
  const float* b1 = (const float*)d_in[3];
  const float* w2 = (const float*)d_in[4];
  const float* b2 = (const float*)d_in[5];
  float* out = (float*)d_out;

  char* ws = (char*)d_ws;
  int* counts      = (int*)ws;                 // 8
  int* offsets     = counts + 8;               // 8
  int* tileExpert  = counts + 16;              // 136
  int* tileRowBase = counts + 16 + MAXTILES;   // 136
  int* topE        = counts + 16 + 2 * MAXTILES;          // 16384
  int* topSlot     = topE + 16384;                        // 16384
  int* rowTok      = topSlot + 16384;                     // 17408
  float* topW      = (float*)(rowTok + MAXROWS);          // 16384
  unsigned short* xbf  = (unsigned short*)(ws + (512 << 10));
  unsigned short* w1T  = xbf + (size_t)NTOK * DIN;        // 16MB each region
  unsigned short* w2T  = w1T + (size_t)NEXP * DIN * DEXP;
  unsigned short* hbuf = w2T + (size_t)NEXP * DEXP * DEXP;
  unsigned short* ybuf = hbuf + (size_t)MAXROWS * DEXP;
  // total ws use: 512KB + 16+16+16 + 34 + 34 MB ≈ 117MB

  hipMemsetAsync(counts, 0, NEXP * sizeof(int), stream);

  convx_kernel<<<(NTOK * DIN / 4) / 256, 256, 0, stream>>>(x, xbf);
  transw_kernel<<<dim3(16, 16, 16), 256, 0, stream>>>(w1, w2, w1T, w2T);
  gate_kernel<<<NTOK / 4, 256, 0, stream>>>(x, gw, out + (size_t)NTOK * DEXP,
                                            counts, topE, topSlot, topW);
  build_kernel<<<1, 256, 0, stream>>>(counts, offsets, tileExpert, tileRowBase, rowTok);
  scatter_kernel<<<NTOK / 256, 256, 0, stream>>>(offsets, topE, topSlot, rowTok);
  gemm1_kernel<<<dim3(8, MAXTILES), 256, 0, stream>>>(xbf, w1T, b1, tileExpert, tileRowBase,
                                                      rowTok, hbuf);
  gemm2_kernel<<<dim3(8, MAXTILES), 256, 0, stream>>>(hbuf, w2T, b2, tileExpert, tileRowBase,
                                                      ybuf);
  combine_kernel<<<NTOK / 4, 256, 0, stream>>>(ybuf, offsets, topE, topSlot, topW, out);
}

// Round 3
// 373.948 us; speedup vs baseline: 2.5490x; 1.4005x over previous
//
#include <hip/hip_runtime.h>
#include <math.h>
#include <stdint.h>

// MoE: B=8192 tokens, D_IN=1024, 8 experts, D_EXP=1024, top-2.
// Pipeline: atomic-free fp64 gating -> single-block slot/prefix-sum ->
// per-expert gathered bf16 MFMA GEMMs -> coalesced weighted combine.

#define NTOK   8192
#define DIN    1024
#define NEXP   8
#define DEXP   1024
#define MAXROWS 17408   // 16384 assignments + per-expert pad to 128
#define MAXTILES 136

typedef __bf16 bf16x8_t __attribute__((ext_vector_type(8)));
typedef float f32x4 __attribute__((ext_vector_type(4)));

__device__ __forceinline__ unsigned short f2bf(float f) {
  union { float f; unsigned int u; } v; v.f = f;
  unsigned int u = v.u;
  u += 0x7fffu + ((u >> 16) & 1u);   // round-to-nearest-even
  return (unsigned short)(u >> 16);
}

__device__ __forceinline__ float bf2f(unsigned short s) {
  union { unsigned int u; float f; } v; v.u = ((unsigned int)s) << 16;
  return v.f;
}

__device__ __forceinline__ void async16(const void* g, void* l) {
  __builtin_amdgcn_global_load_lds((const __attribute__((address_space(1))) void*)g,
                                   (__attribute__((address_space(3))) void*)l, 16, 0, 0);
}

// ---------------- x fp32 -> bf16 ----------------
__global__ __launch_bounds__(256) void convx_kernel(const float* __restrict__ x,
                                                    unsigned short* __restrict__ xbf) {
  int gid = blockIdx.x * 256 + threadIdx.x;
  float4 v = ((const float4*)x)[gid];
  ushort4 r;
  r.x = f2bf(v.x); r.y = f2bf(v.y); r.z = f2bf(v.z); r.w = f2bf(v.w);
  ((ushort4*)xbf)[gid] = r;
}

// ---------------- w1/w2 fp32 [e][k][n] -> bf16 [e][n][k] (transpose+cast) ----------------
__global__ __launch_bounds__(256) void transw_kernel(const float* __restrict__ w1,
                                                     const float* __restrict__ w2,
                                                     unsigned short* __restrict__ w1T,
                                                     unsigned short* __restrict__ w2T) {
  int bz = blockIdx.z;                                // 0..15: 0-7 -> w1, 8-15 -> w2
  const float* src = (bz < 8) ? w1 : w2;
  unsigned short* dst = (bz < 8) ? w1T : w2T;
  int e = bz & 7;
  int kt = blockIdx.y, nt = blockIdx.x;
  __shared__ float tile[64][65];
  int tid = threadIdx.x;
  int c = tid & 63, r4 = tid >> 6;
  const float* s = src + (size_t)e * DIN * DEXP;
  #pragma unroll
  for (int i = 0; i < 16; ++i) {
    int r = i * 4 + r4;
    tile[r][c] = s[(size_t)(kt * 64 + r) * 1024 + nt * 64 + c];
  }
  __syncthreads();
  unsigned short* d = dst + (size_t)e * DIN * DEXP;
  #pragma unroll
  for (int i = 0; i < 16; ++i) {
    int r = i * 4 + r4;
    d[(size_t)(nt * 64 + r) * 1024 + kt * 64 + c] = f2bf(tile[c][r]);
  }
}

// ---------------- gating: fp64 logits, top-2, softmax. NO atomics, NO LDS. ----------------
__global__ __launch_bounds__(256) void gate_kernel(const float* __restrict__ x,
                                                   const float* __restrict__ gw,
                                                   float* __restrict__ outGate,
                                                   int* __restrict__ topE,
                                                   float* __restrict__ topW) {
  int tid = threadIdx.x, lane = tid & 63, wv = tid >> 6;
  int t = blockIdx.x * 4 + wv;
  const float* xr = x + (size_t)t * 1024;
  double acc[NEXP];
  #pragma unroll
  for (int e = 0; e < NEXP; ++e) acc[e] = 0.0;
  for (int j = 0; j < 16; ++j) {
    int k = j * 64 + lane;
    double xv = (double)xr[k];
    float4 g0 = *(const float4*)(gw + k * 8);       // gw[k][0..3], L1-resident
    float4 g1 = *(const float4*)(gw + k * 8 + 4);
    acc[0] += xv * (double)g0.x; acc[1] += xv * (double)g0.y;
    acc[2] += xv * (double)g0.z; acc[3] += xv * (double)g0.w;
    acc[4] += xv * (double)g1.x; acc[5] += xv * (double)g1.y;
    acc[6] += xv * (double)g1.z; acc[7] += xv * (double)g1.w;
  }
  #pragma unroll
  for (int off = 32; off > 0; off >>= 1) {
    #pragma unroll
    for (int e = 0; e < NEXP; ++e) acc[e] += __shfl_xor(acc[e], off);
  }
  if (lane == 0) {
    int e0 = 0; double v0 = acc[0];
    #pragma unroll
    for (int e = 1; e < NEXP; ++e) if (acc[e] > v0) { v0 = acc[e]; e0 = e; }
    int e1 = -1; double v1 = -1e300;
    #pragma unroll
    for (int e = 0; e < NEXP; ++e) if (e != e0 && acc[e] > v1) { v1 = acc[e]; e1 = e; }
    float ex = expf((float)(v1 - v0));
    float inv = 1.0f / (1.0f + ex);
    float w0 = inv, w1 = ex * inv;
    float g8[8];
    #pragma unroll
    for (int e = 0; e < NEXP; ++e) g8[e] = 0.f;
    g8[e0] = w0; g8[e1] = w1;
    float4* gp = (float4*)(outGate + t * 8);
    gp[0] = *(float4*)&g8[0];
    gp[1] = *(float4*)&g8[4];
    topE[t * 2 + 0] = e0; topE[t * 2 + 1] = e1;
    topW[t * 2 + 0] = w0; topW[t * 2 + 1] = w1;
  }
}

// ---------------- slots, tile table, rowTok, topRow: one block, prefix sums ----------------
__global__ __launch_bounds__(1024) void slot_kernel(const int* __restrict__ topE,
                                                    int* __restrict__ topRow,
                                                    int* __restrict__ rowTok,
                                                    int* __restrict__ tileExpert,
                                                    int* __restrict__ tileRowBase) {
  __shared__ int wtot[16][NEXP];
  __shared__ int wbase[16][NEXP];
  __shared__ int soff[NEXP];
  int tid = threadIdx.x, lane = tid & 63, wv = tid >> 6;
  for (int i = tid; i < MAXROWS; i += 1024) rowTok[i] = -1;
  // phase 1: per-thread histogram over 16 assignments (packed 4 bits each)
  int a0 = tid * 16;
  unsigned long long pk = 0ull;
  int cnt[NEXP];
  #pragma unroll
  for (int e = 0; e < NEXP; ++e) cnt[e] = 0;
  for (int i = 0; i < 16; ++i) {
    int e = topE[a0 + i];
    pk |= (unsigned long long)e << (i * 4);
    cnt[e]++;
  }
  // phase 2: wave exclusive scan per expert
  int excl[NEXP];
  #pragma unroll
  for (int e = 0; e < NEXP; ++e) {
    int v = cnt[e], sum = v;
    #pragma unroll
    for (int d = 1; d < 64; d <<= 1) {
      int u = __shfl_up(sum, d);
      if (lane >= d) sum += u;
    }
    excl[e] = sum - v;
    if (lane == 63) wtot[wv][e] = sum;
  }
  __syncthreads();
  // phase 3: cross-wave scan + padded segment offsets + tile table (thread 0)
  if (tid == 0) {
    int counts[NEXP];
    for (int e = 0; e < NEXP; ++e) {
      int s = 0;
      for (int w = 0; w < 16; ++w) { wbase[w][e] = s; s += wtot[w][e]; }
      counts[e] = s;
    }
    int row = 0, tile = 0;
    for (int e = 0; e < NEXP; ++e) {
      soff[e] = row;
      int nt = (counts[e] + 127) >> 7;
      for (int i = 0; i < nt; ++i) { tileExpert[tile] = e; tileRowBase[tile] = row + i * 128; ++tile; }
      row += nt << 7;
    }
    for (; tile < MAXTILES; ++tile) tileExpert[tile] = -1;
  }
  __syncthreads();
  // phase 4: assign rows
  int base[NEXP], run[NEXP];
  #pragma unroll
  for (int e = 0; e < NEXP; ++e) { base[e] = soff[e] + wbase[wv][e] + excl[e]; run[e] = 0; }
  for (int i = 0; i < 16; ++i) {
    int e = (int)((pk >> (i * 4)) & 7ull);
    int row = base[e] + run[e]++;
    rowTok[row] = (a0 + i) >> 1;
    topRow[a0 + i] = row;
  }
}

// ---------------- GEMM1: h = gelu(Xg @ W1[e] + b1[e]), bf16 out ----------------
__global__ __launch_bounds__(256) void gemm1_kernel(const unsigned short* __restrict__ xbf,
                                                    const unsigned short* __restrict__ w1T,
                                                    const float* __restrict__ b1,
                                                    const int* __restrict__ tileExpert,
                                                    const int* __restrict__ tileRowBase,
                                                    const int* __restrict__ rowTok,
                                                    unsigned short* __restrict__ h) {
  int tileId = blockIdx.y;
  int e = tileExpert[tileId];
  if (e < 0) return;
  int rowBase = tileRowBase[tileId];
  int n0 = blockIdx.x * 128;
  __shared__ __align__(16) unsigned short sm[128 * 64 * 2];  // 32KB: sA | sB
  unsigned short* sA = sm;
  unsigned short* sB = sm + 128 * 64;
  int tid = threadIdx.x, lane = tid & 63, wv = tid >> 6;
  int srow = tid >> 3;            // 0..31 (+32 per issue)
  int scol = (tid & 7) * 8;       // k element within BK=64
  int tok[4];
  #pragma unroll
  for (int i = 0; i < 4; ++i) {
    int tk = rowTok[rowBase + srow + i * 32];
    tok[i] = tk < 0 ? 0 : tk;
  }
  const unsigned short* Bmat = w1T + (size_t)e * DIN * DEXP;
  int wm = ((tid >> 6) & 1) * 64, wn = (tid >> 7) * 64;
  int rsel = lane & 15, q8 = (lane >> 4) * 8;
  f32x4 acc[4][4] = {};
  for (int kk = 0; kk < DIN; kk += 64) {
    #pragma unroll
    for (int i = 0; i < 4; ++i) {
      int abase = __builtin_amdgcn_readfirstlane((wv * 8 + i * 32) * 128);
      async16(xbf + (size_t)tok[i] * 1024 + kk + scol, (char*)sm + abase);
      async16(Bmat + (size_t)(n0 + srow + i * 32) * 1024 + kk + scol,
              (char*)sm + abase + 16384);
    }
    __syncthreads();
    #pragma unroll
    for (int ks = 0; ks < 64; ks += 32) {
      bf16x8_t af[4], bfr[4];
      #pragma unroll
      for (int mi = 0; mi < 4; ++mi)
        af[mi] = *(const bf16x8_t*)&sA[(wm + mi * 16 + rsel) * 64 + ks + q8];
      #pragma unroll
      for (int ni = 0; ni < 4; ++ni)
        bfr[ni] = *(const bf16x8_t*)&sB[(wn + ni * 16 + rsel) * 64 + ks + q8];
      #pragma unroll
      for (int mi = 0; mi < 4; ++mi)
        #pragma unroll
        for (int ni = 0; ni < 4; ++ni)
          acc[mi][ni] = __builtin_amdgcn_mfma_f32_16x16x32_bf16(af[mi], bfr[ni], acc[mi][ni], 0, 0, 0);
    }
    __syncthreads();
  }
  float b1v[4];
  int quad = lane >> 4;
  #pragma unroll
  for (int ni = 0; ni < 4; ++ni) b1v[ni] = b1[e * 1024 + n0 + wn + ni * 16 + rsel];
  #pragma unroll
  for (int mi = 0; mi < 4; ++mi)
    #pragma unroll
    for (int ni = 0; ni < 4; ++ni)
      #pragma unroll
      for (int r = 0; r < 4; ++r) {
        int m = wm + mi * 16 + quad * 4 + r;
        int n = wn + ni * 16 + rsel;
        float v = acc[mi][ni][r] + b1v[ni];
        v = 0.5f * v * (1.0f + erff(v * 0.70710678118654752f));
        sm[m * 128 + n] = f2bf(v);
      }
  __syncthreads();
  #pragma unroll
  for (int i = 0; i < 8; ++i) {
    int idx = i * 2048 + tid * 8;
    int m = idx >> 7, c = idx & 127;
    int g = rowBase + m;
    *(uint4*)(h + (size_t)g * 1024 + n0 + c) = *(const uint4*)&sm[idx];
  }
}

// ---------------- GEMM2: y[row] = h[row] @ W2[e] + b2[e] (bf16) ----------------
__global__ __launch_bounds__(256) void gemm2_kernel(const unsigned short* __restrict__ h,
                                                    const unsigned short* __restrict__ w2T,
                                                    const float* __restrict__ b2,
                                                    const int* __restrict__ tileExpert,
                                                    const int* __restrict__ tileRowBase,
                                                    unsigned short* __restrict__ y) {
  int tileId = blockIdx.y;
  int e = tileExpert[tileId];
  if (e < 0) return;
  int rowBase = tileRowBase[tileId];
  int n0 = blockIdx.x * 128;
  __shared__ __align__(16) unsigned short sm[128 * 64 * 2];
  unsigned short* sA = sm;
  unsigned short* sB = sm + 128 * 64;
  int tid = threadIdx.x, lane = tid & 63, wv = tid >> 6;
  int srow = tid >> 3;
  int scol = (tid & 7) * 8;
  const unsigned short* Bmat = w2T + (size_t)e * DEXP * DEXP;
  int wm = ((tid >> 6) & 1) * 64, wn = (tid >> 7) * 64;
  int rsel = lane & 15, q8 = (lane >> 4) * 8;
  f32x4 acc[4][4] = {};
  for (int kk = 0; kk < DEXP; kk += 64) {
    #pragma unroll
    for (int i = 0; i < 4; ++i) {
      int abase = __builtin_amdgcn_readfirstlane((wv * 8 + i * 32) * 128);
      async16(h + (size_t)(rowBase + srow + i * 32) * 1024 + kk + scol, (char*)sm + abase);
      async16(Bmat + (size_t)(n0 + srow + i * 32) * 1024 + kk + scol,
              (char*)sm + abase + 16384);
    }
    __syncthreads();
    #pragma unroll
    for (int ks = 0; ks < 64; ks += 32) {
      bf16x8_t af[4], bfr[4];
      #pragma unroll
      for (int mi = 0; mi < 4; ++mi)
        af[mi] = *(const bf16x8_t*)&sA[(wm + mi * 16 + rsel) * 64 + ks + q8];
      #pragma unroll
      for (int ni = 0; ni < 4; ++ni)
        bfr[ni] = *(const bf16x8_t*)&sB[(wn + ni * 16 + rsel) * 64 + ks + q8];
      #pragma unroll
      for (int mi = 0; mi < 4; ++mi)
        #pragma unroll
        for (int ni = 0; ni < 4; ++ni)
          acc[mi][ni] = __builtin_amdgcn_mfma_f32_16x16x32_bf16(af[mi], bfr[ni], acc[mi][ni], 0, 0, 0);
    }
    __syncthreads();
  }
  float b2v[4];
  int quad = lane >> 4;
  #pragma unroll
  for (int ni = 0; ni < 4; ++ni) b2v[ni] = b2[e * 1024 + n0 + wn + ni * 16 + rsel];
  #pragma unroll
  for (int mi = 0; mi < 4; ++mi)
    #pragma unroll
    for (int ni = 0; ni < 4; ++ni)
      #pragma unroll
      for (int r = 0; r < 4; ++r) {
        int m = wm + mi * 16 + quad * 4 + r;
        int n = wn + ni * 16 + rsel;
        sm[m * 128 + n] = f2bf(acc[mi][ni][r] + b2v[ni]);
      }
  __syncthreads();
  #pragma unroll
  for (int i = 0; i < 8; ++i) {
    int idx = i * 2048 + tid * 8;
    int m = idx >> 7, c = idx & 127;
    int g = rowBase + m;
    *(uint4*)(y + (size_t)g * 1024 + n0 + c) = *(const uint4*)&sm[idx];
  }
}

// ---------------- combine: out[t] = w0*y[r0] + w1*y[r1] ----------------
__global__ __launch_bounds__(256) void combine_kernel(const unsigned short* __restrict__ y,
                                                      const int* __restrict__ topRow,
                                                      const float* __restrict__ topW,
                                                      float* __restrict__ out) {
  int tid = threadIdx.x;
  int wv = tid >> 6, lane = tid & 63;
  int t = blockIdx.x * 4 + wv;
  int r0 = topRow[t * 2 + 0], r1 = topRow[t * 2 + 1];
  float w0 = topW[t * 2 + 0], w1 = topW[t * 2 + 1];
  const unsigned short* p0 = y + (size_t)r0 * 1024 + lane * 16;
  const unsigned short* p1 = y + (size_t)r1 * 1024 + lane * 16;
  float* op = out + (size_t)t * 1024 + lane * 16;
  #pragma unroll
  for (int hh = 0; hh < 2; ++hh) {
    union { uint4 v; unsigned short s[8]; } a, b;
    a.v = *(const uint4*)(p0 + hh * 8);
    b.v = *(const uint4*)(p1 + hh * 8);
    float o[8];
    #pragma unroll
    for (int j = 0; j < 8; ++j)
      o[j] = w0 * bf2f(a.s[j]) + w1 * bf2f(b.s[j]);
    *(float4*)(op + hh * 8) = *(float4*)&o[0];
    *(float4*)(op + hh * 8 + 4) = *(float4*)&o[4];
  }
}

extern "C" void kernel_launch(void* const* d_in, const int* in_sizes, int n_in,
                              void* d_out, int out_size, void* d_ws, size_t ws_size,
                              hipStream_t stream) {
  const float* x  = (const float*)d_in[0];
  const float* gw = (const float*)d_in[1];
  const float* w1 = (const float*)d_in[2];
  const float* b1 = (const float*)d_in[3];
  const float* w2 = (const float*)d_in[4];
  const float* b2 = (const float*)d_in[5];
  float* out = (float*)d_out;

  char* ws = (char*)d_ws;
  int* tileExpert  = (int*)ws;                            // 136
  int* tileRowBase = tileExpert + MAXTILES;               // 136
  int* topE        = tileRowBase + MAXTILES;              // 16384
  int* topRow      = topE + 16384;                        // 16384
  int* rowTok      = topRow + 16384;                      // 17408
  float* topW      = (float*)(rowTok + MAXROWS);          // 16384
  unsigned short* xbf  = (unsigned short*)(ws + (512 << 10));
  unsigned short* w1T  = xbf + (size_t)NTOK * DIN;
  unsigned short* w2T  = w1T + (size_t)NEXP * DIN * DEXP;
  unsigned short* hbuf = w2T + (size_t)NEXP * DEXP * DEXP;
  unsigned short* ybuf = hbuf + (size_t)MAXROWS * DEXP;

  convx_kernel<<<(NTOK * DIN / 4) / 256, 256, 0, stream>>>(x, xbf);
  transw_kernel<<<dim3(16, 16, 16), 256, 0, stream>>>(w1, w2, w1T, w2T);
  gate_kernel<<<NTOK / 4, 256, 0, stream>>>(x, gw, out + (size_t)NTOK * DEXP,
                                            topE, topW);
  slot_kernel<<<1, 1024, 0, stream>>>(topE, topRow, rowTok, tileExpert, tileRowBase);
  gemm1_kernel<<<dim3(8, MAXTILES), 256, 0, stream>>>(xbf, w1T, b1, tileExpert, tileRowBase,
                                                      rowTok, hbuf);
  gemm2_kernel<<<dim3(8, MAXTILES), 256, 0, stream>>>(hbuf, w2T, b2, tileExpert, tileRowBase,
                                                      ybuf);
  combine_kernel<<<NTOK / 4, 256, 0, stream>>>(ybuf, topRow, topW, out);
}

// Round 4
// 340.175 us; speedup vs baseline: 2.8020x; 1.0993x over previous
//
#include <hip/hip_runtime.h>
#include <math.h>
#include <stdint.h>

// MoE: B=8192 tokens, D_IN=1024, 8 experts, D_EXP=1024, top-2.
// Pipeline: fused convx+fp64 gating -> single-block slot assign ->
// per-expert gathered bf16 MFMA GEMMs (XOR-swizzled LDS) -> weighted combine.

#define NTOK   8192
#define DIN    1024
#define NEXP   8
#define DEXP   1024
#define MAXROWS 17408   // 16384 assignments + per-expert pad to 128
#define MAXTILES 136

typedef __bf16 bf16x8_t __attribute__((ext_vector_type(8)));
typedef float f32x4 __attribute__((ext_vector_type(4)));

__device__ __forceinline__ unsigned short f2bf(float f) {
  union { float f; unsigned int u; } v; v.f = f;
  unsigned int u = v.u;
  u += 0x7fffu + ((u >> 16) & 1u);   // round-to-nearest-even
  return (unsigned short)(u >> 16);
}

__device__ __forceinline__ float bf2f(unsigned short s) {
  union { unsigned int u; float f; } v; v.u = ((unsigned int)s) << 16;
  return v.f;
}

__device__ __forceinline__ void async16(const void* g, void* l) {
  __builtin_amdgcn_global_load_lds((const __attribute__((address_space(1))) void*)g,
                                   (__attribute__((address_space(3))) void*)l, 16, 0, 0);
}

// fast exact-enough GELU: tanh form via sigmoid, max abs err ~3e-4
__device__ __forceinline__ float gelu_fast(float v) {
  // 0.5v(1+tanh(sqrt(2/pi)(v+0.044715v^3))) = v * sigmoid(2*sqrt(2/pi)*(v+0.044715v^3))
  float u = v * (1.5957691216057308f + 0.07135481627f * v * v); // 2*sqrt(2/pi)*(1, 0.044715)
  return v * (1.0f / (1.0f + __expf(-u)));
}

// ---------------- fused: x fp32 -> bf16 cast + fp64 gating ----------------
__global__ __launch_bounds__(256) void convx_gate_kernel(const float* __restrict__ x,
                                                         const float* __restrict__ gw,
                                                         unsigned short* __restrict__ xbf,
                                                         float* __restrict__ outGate,
                                                         int* __restrict__ topE,
                                                         float* __restrict__ topW) {
  int tid = threadIdx.x, lane = tid & 63, wv = tid >> 6;
  int t = blockIdx.x * 4 + wv;
  const float4* xr = (const float4*)(x + (size_t)t * 1024);
  ushort4* xo = (ushort4*)(xbf + (size_t)t * 1024);
  double acc[NEXP];
  #pragma unroll
  for (int e = 0; e < NEXP; ++e) acc[e] = 0.0;
  #pragma unroll
  for (int j = 0; j < 4; ++j) {
    int q = lane + 64 * j;
    float4 v = xr[q];
    ushort4 r;
    r.x = f2bf(v.x); r.y = f2bf(v.y); r.z = f2bf(v.z); r.w = f2bf(v.w);
    xo[q] = r;
    float vv[4] = {v.x, v.y, v.z, v.w};
    #pragma unroll
    for (int m = 0; m < 4; ++m) {
      int k = q * 4 + m;
      float4 g0 = *(const float4*)(gw + k * 8);
      float4 g1 = *(const float4*)(gw + k * 8 + 4);
      double xv = (double)vv[m];
      acc[0] += xv * (double)g0.x; acc[1] += xv * (double)g0.y;
      acc[2] += xv * (double)g0.z; acc[3] += xv * (double)g0.w;
      acc[4] += xv * (double)g1.x; acc[5] += xv * (double)g1.y;
      acc[6] += xv * (double)g1.z; acc[7] += xv * (double)g1.w;
    }
  }
  #pragma unroll
  for (int off = 32; off > 0; off >>= 1) {
    #pragma unroll
    for (int e = 0; e < NEXP; ++e) acc[e] += __shfl_xor(acc[e], off);
  }
  if (lane == 0) {
    int e0 = 0; double v0 = acc[0];
    #pragma unroll
    for (int e = 1; e < NEXP; ++e) if (acc[e] > v0) { v0 = acc[e]; e0 = e; }
    int e1 = -1; double v1 = -1e300;
    #pragma unroll
    for (int e = 0; e < NEXP; ++e) if (e != e0 && acc[e] > v1) { v1 = acc[e]; e1 = e; }
    float ex = expf((float)(v1 - v0));
    float inv = 1.0f / (1.0f + ex);
    float w0 = inv, w1 = ex * inv;
    float g8[8];
    #pragma unroll
    for (int e = 0; e < NEXP; ++e) g8[e] = 0.f;
    g8[e0] = w0; g8[e1] = w1;
    float4* gp = (float4*)(outGate + t * 8);
    gp[0] = *(float4*)&g8[0];
    gp[1] = *(float4*)&g8[4];
    topE[t * 2 + 0] = e0; topE[t * 2 + 1] = e1;
    topW[t * 2 + 0] = w0; topW[t * 2 + 1] = w1;
  }
}

// ---------------- w1/w2 fp32 [e][k][n] -> bf16 [e][n][k] (transpose+cast) ----------------
__global__ __launch_bounds__(256) void transw_kernel(const float* __restrict__ w1,
                                                     const float* __restrict__ w2,
                                                     unsigned short* __restrict__ w1T,
                                                     unsigned short* __restrict__ w2T) {
  int bz = blockIdx.z;
  const float* src = (bz < 8) ? w1 : w2;
  unsigned short* dst = (bz < 8) ? w1T : w2T;
  int e = bz & 7;
  int kt = blockIdx.y, nt = blockIdx.x;
  __shared__ float tile[64][65];
  int tid = threadIdx.x;
  int c = tid & 63, r4 = tid >> 6;
  const float* s = src + (size_t)e * DIN * DEXP;
  #pragma unroll
  for (int i = 0; i < 16; ++i) {
    int r = i * 4 + r4;
    tile[r][c] = s[(size_t)(kt * 64 + r) * 1024 + nt * 64 + c];
  }
  __syncthreads();
  unsigned short* d = dst + (size_t)e * DIN * DEXP;
  #pragma unroll
  for (int i = 0; i < 16; ++i) {
    int r = i * 4 + r4;
    d[(size_t)(nt * 64 + r) * 1024 + kt * 64 + c] = f2bf(tile[c][r]);
  }
}

// ---------------- slots, tile table, rowTok, topRow: one block ----------------
__global__ __launch_bounds__(1024) void slot_kernel(const int* __restrict__ topE,
                                                    int* __restrict__ topRow,
                                                    int* __restrict__ rowTok,
                                                    int* __restrict__ tileExpert,
                                                    int* __restrict__ tileRowBase) {
  __shared__ int wtot[16][NEXP];
  __shared__ int wbase[16][NEXP];
  __shared__ int soff[NEXP];
  int tid = threadIdx.x, lane = tid & 63, wv = tid >> 6;
  for (int i = tid; i < MAXROWS; i += 1024) rowTok[i] = -1;
  int a0 = tid * 16;
  unsigned long long pk = 0ull;
  int cnt[NEXP];
  #pragma unroll
  for (int e = 0; e < NEXP; ++e) cnt[e] = 0;
  for (int i = 0; i < 16; ++i) {
    int e = topE[a0 + i];
    pk |= (unsigned long long)e << (i * 4);
    cnt[e]++;
  }
  int excl[NEXP];
  #pragma unroll
  for (int e = 0; e < NEXP; ++e) {
    int v = cnt[e], sum = v;
    #pragma unroll
    for (int d = 1; d < 64; d <<= 1) {
      int u = __shfl_up(sum, d);
      if (lane >= d) sum += u;
    }
    excl[e] = sum - v;
    if (lane == 63) wtot[wv][e] = sum;
  }
  __syncthreads();
  if (tid == 0) {
    int counts[NEXP];
    for (int e = 0; e < NEXP; ++e) {
      int s = 0;
      for (int w = 0; w < 16; ++w) { wbase[w][e] = s; s += wtot[w][e]; }
      counts[e] = s;
    }
    int row = 0, tile = 0;
    for (int e = 0; e < NEXP; ++e) {
      soff[e] = row;
      int nt = (counts[e] + 127) >> 7;
      for (int i = 0; i < nt; ++i) { tileExpert[tile] = e; tileRowBase[tile] = row + i * 128; ++tile; }
      row += nt << 7;
    }
    for (; tile < MAXTILES; ++tile) tileExpert[tile] = -1;
  }
  __syncthreads();
  int base[NEXP], run[NEXP];
  #pragma unroll
  for (int e = 0; e < NEXP; ++e) { base[e] = soff[e] + wbase[wv][e] + excl[e]; run[e] = 0; }
  for (int i = 0; i < 16; ++i) {
    int e = (int)((pk >> (i * 4)) & 7ull);
    int row = base[e] + run[e]++;
    rowTok[row] = (a0 + i) >> 1;
    topRow[a0 + i] = row;
  }
}

// ---------------- GEMM1: h = gelu(Xg @ W1[e] + b1[e]), bf16 out ----------------
// LDS k-chunk XOR swizzle: LDS[row][slot] holds global chunk slot^(row&7);
// reads of chunk c use slot c^(row&7) -> all 32 banks active.
__global__ __launch_bounds__(256) void gemm1_kernel(const unsigned short* __restrict__ xbf,
                                                    const unsigned short* __restrict__ w1T,
                                                    const float* __restrict__ b1,
                                                    const int* __restrict__ tileExpert,
                                                    const int* __restrict__ tileRowBase,
                                                    const int* __restrict__ rowTok,
                                                    unsigned short* __restrict__ h) {
  int tileId = blockIdx.y;
  int e = tileExpert[tileId];
  if (e < 0) return;
  int rowBase = tileRowBase[tileId];
  int n0 = blockIdx.x * 128;
  __shared__ __align__(16) unsigned short sm[128 * 64 * 2];  // 32KB: sA | sB
  unsigned short* sA = sm;
  unsigned short* sB = sm + 128 * 64;
  int tid = threadIdx.x, lane = tid & 63, wv = tid >> 6;
  int srow = tid >> 3;                       // 0..31 (+32 per issue)
  int scolSw = (((tid & 7) ^ ((tid >> 3) & 7)) * 8);   // swizzled k-chunk fetch
  int tok[4];
  #pragma unroll
  for (int i = 0; i < 4; ++i) {
    int tk = rowTok[rowBase + srow + i * 32];
    tok[i] = tk < 0 ? 0 : tk;
  }
  const unsigned short* Bmat = w1T + (size_t)e * DIN * DEXP;
  int wm = ((tid >> 6) & 1) * 64, wn = (tid >> 7) * 64;
  int rsel = lane & 15, q = lane >> 4;
  int rk = rsel & 7;
  f32x4 acc[4][4] = {};
  for (int kk = 0; kk < DIN; kk += 64) {
    #pragma unroll
    for (int i = 0; i < 4; ++i) {
      int abase = __builtin_amdgcn_readfirstlane((wv * 8 + i * 32) * 128);
      async16(xbf + (size_t)tok[i] * 1024 + kk + scolSw, (char*)sm + abase);
      async16(Bmat + (size_t)(n0 + srow + i * 32) * 1024 + kk + scolSw,
              (char*)sm + abase + 16384);
    }
    __syncthreads();
    #pragma unroll
    for (int ks = 0; ks < 64; ks += 32) {
      int co = (((ks >> 3) + q) ^ rk) * 8;   // swizzled element offset in row
      bf16x8_t af[4], bfr[4];
      #pragma unroll
      for (int mi = 0; mi < 4; ++mi)
        af[mi] = *(const bf16x8_t*)&sA[(wm + mi * 16 + rsel) * 64 + co];
      #pragma unroll
      for (int ni = 0; ni < 4; ++ni)
        bfr[ni] = *(const bf16x8_t*)&sB[(wn + ni * 16 + rsel) * 64 + co];
      #pragma unroll
      for (int mi = 0; mi < 4; ++mi)
        #pragma unroll
        for (int ni = 0; ni < 4; ++ni)
          acc[mi][ni] = __builtin_amdgcn_mfma_f32_16x16x32_bf16(af[mi], bfr[ni], acc[mi][ni], 0, 0, 0);
    }
    __syncthreads();
  }
  float b1v[4];
  int quad = lane >> 4;
  #pragma unroll
  for (int ni = 0; ni < 4; ++ni) b1v[ni] = b1[e * 1024 + n0 + wn + ni * 16 + rsel];
  #pragma unroll
  for (int mi = 0; mi < 4; ++mi)
    #pragma unroll
    for (int ni = 0; ni < 4; ++ni)
      #pragma unroll
      for (int r = 0; r < 4; ++r) {
        int m = wm + mi * 16 + quad * 4 + r;
        int n = wn + ni * 16 + rsel;
        sm[m * 128 + n] = f2bf(gelu_fast(acc[mi][ni][r] + b1v[ni]));
      }
  __syncthreads();
  #pragma unroll
  for (int i = 0; i < 8; ++i) {
    int idx = i * 2048 + tid * 8;
    int m = idx >> 7, c = idx & 127;
    int g = rowBase + m;
    *(uint4*)(h + (size_t)g * 1024 + n0 + c) = *(const uint4*)&sm[idx];
  }
}

// ---------------- GEMM2: y[row] = h[row] @ W2[e] + b2[e] (bf16) ----------------
__global__ __launch_bounds__(256) void gemm2_kernel(const unsigned short* __restrict__ h,
                                                    const unsigned short* __restrict__ w2T,
                                                    const float* __restrict__ b2,
                                                    const int* __restrict__ tileExpert,
                                                    const int* __restrict__ tileRowBase,
                                                    unsigned short* __restrict__ y) {
  int tileId = blockIdx.y;
  int e = tileExpert[tileId];
  if (e < 0) return;
  int rowBase = tileRowBase[tileId];
  int n0 = blockIdx.x * 128;
  __shared__ __align__(16) unsigned short sm[128 * 64 * 2];
  unsigned short* sA = sm;
  unsigned short* sB = sm + 128 * 64;
  int tid = threadIdx.x, lane = tid & 63, wv = tid >> 6;
  int srow = tid >> 3;
  int scolSw = (((tid & 7) ^ ((tid >> 3) & 7)) * 8);
  const unsigned short* Bmat = w2T + (size_t)e * DEXP * DEXP;
  int wm = ((tid >> 6) & 1) * 64, wn = (tid >> 7) * 64;
  int rsel = lane & 15, q = lane >> 4;
  int rk = rsel & 7;
  f32x4 acc[4][4] = {};
  for (int kk = 0; kk < DEXP; kk += 64) {
    #pragma unroll
    for (int i = 0; i < 4; ++i) {
      int abase = __builtin_amdgcn_readfirstlane((wv * 8 + i * 32) * 128);
      async16(h + (size_t)(rowBase + srow + i * 32) * 1024 + kk + scolSw, (char*)sm + abase);
      async16(Bmat + (size_t)(n0 + srow + i * 32) * 1024 + kk + scolSw,
              (char*)sm + abase + 16384);
    }
    __syncthreads();
    #pragma unroll
    for (int ks = 0; ks < 64; ks += 32) {
      int co = (((ks >> 3) + q) ^ rk) * 8;
      bf16x8_t af[4], bfr[4];
      #pragma unroll
      for (int mi = 0; mi < 4; ++mi)
        af[mi] = *(const bf16x8_t*)&sA[(wm + mi * 16 + rsel) * 64 + co];
      #pragma unroll
      for (int ni = 0; ni < 4; ++ni)
        bfr[ni] = *(const bf16x8_t*)&sB[(wn + ni * 16 + rsel) * 64 + co];
      #pragma unroll
      for (int mi = 0; mi < 4; ++mi)
        #pragma unroll
        for (int ni = 0; ni < 4; ++ni)
          acc[mi][ni] = __builtin_amdgcn_mfma_f32_16x16x32_bf16(af[mi], bfr[ni], acc[mi][ni], 0, 0, 0);
    }
    __syncthreads();
  }
  float b2v[4];
  int quad = lane >> 4;
  #pragma unroll
  for (int ni = 0; ni < 4; ++ni) b2v[ni] = b2[e * 1024 + n0 + wn + ni * 16 + rsel];
  #pragma unroll
  for (int mi = 0; mi < 4; ++mi)
    #pragma unroll
    for (int ni = 0; ni < 4; ++ni)
      #pragma unroll
      for (int r = 0; r < 4; ++r) {
        int m = wm + mi * 16 + quad * 4 + r;
        int n = wn + ni * 16 + rsel;
        sm[m * 128 + n] = f2bf(acc[mi][ni][r] + b2v[ni]);
      }
  __syncthreads();
  #pragma unroll
  for (int i = 0; i < 8; ++i) {
    int idx = i * 2048 + tid * 8;
    int m = idx >> 7, c = idx & 127;
    int g = rowBase + m;
    *(uint4*)(y + (size_t)g * 1024 + n0 + c) = *(const uint4*)&sm[idx];
  }
}

// ---------------- combine: out[t] = w0*y[r0] + w1*y[r1] ----------------
__global__ __launch_bounds__(256) void combine_kernel(const unsigned short* __restrict__ y,
                                                      const int* __restrict__ topRow,
                                                      const float* __restrict__ topW,
                                                      float* __restrict__ out) {
  int tid = threadIdx.x;
  int wv = tid >> 6, lane = tid & 63;
  int t = blockIdx.x * 4 + wv;
  int r0 = topRow[t * 2 + 0], r1 = topRow[t * 2 + 1];
  float w0 = topW[t * 2 + 0], w1 = topW[t * 2 + 1];
  const unsigned short* p0 = y + (size_t)r0 * 1024 + lane * 16;
  const unsigned short* p1 = y + (size_t)r1 * 1024 + lane * 16;
  float* op = out + (size_t)t * 1024 + lane * 16;
  #pragma unroll
  for (int hh = 0; hh < 2; ++hh) {
    union { uint4 v; unsigned short s[8]; } a, b;
    a.v = *(const uint4*)(p0 + hh * 8);
    b.v = *(const uint4*)(p1 + hh * 8);
    float o[8];
    #pragma unroll
    for (int j = 0; j < 8; ++j)
      o[j] = w0 * bf2f(a.s[j]) + w1 * bf2f(b.s[j]);
    *(float4*)(op + hh * 8) = *(float4*)&o[0];
    *(float4*)(op + hh * 8 + 4) = *(float4*)&o[4];
  }
}

extern "C" void kernel_launch(void* const* d_in, const int* in_sizes, int n_in,
                              void* d_out, int out_size, void* d_ws, size_t ws_size,
                              hipStream_t stream) {
  const float* x  = (const float*)d_in[0];
  const float* gw = (const float*)d_in[1];
  const float* w1 = (const float*)d_in[2];
  const float* b1 = (const float*)d_in[3];
  const float* w2 = (const float*)d_in[4];
  const float* b2 = (const float*)d_in[5];
  float* out = (float*)d_out;

  char* ws = (char*)d_ws;
  int* tileExpert  = (int*)ws;                            // 136
  int* tileRowBase = tileExpert + MAXTILES;               // 136
  int* topE        = tileRowBase + MAXTILES;              // 16384
  int* topRow      = topE + 16384;                        // 16384
  int* rowTok      = topRow + 16384;                      // 17408
  float* topW      = (float*)(rowTok + MAXROWS);          // 16384
  unsigned short* xbf  = (unsigned short*)(ws + (512 << 10));
  unsigned short* w1T  = xbf + (size_t)NTOK * DIN;
  unsigned short* w2T  = w1T + (size_t)NEXP * DIN * DEXP;
  unsigned short* hbuf = w2T + (size_t)NEXP * DEXP * DEXP;
  unsigned short* ybuf = hbuf + (size_t)MAXROWS * DEXP;

  transw_kernel<<<dim3(16, 16, 16), 256, 0, stream>>>(w1, w2, w1T, w2T);
  convx_gate_kernel<<<NTOK / 4, 256, 0, stream>>>(x, gw, xbf,
                                                  out + (size_t)NTOK * DEXP, topE, topW);
  slot_kernel<<<1, 1024, 0, stream>>>(topE, topRow, rowTok, tileExpert, tileRowBase);
  gemm1_kernel<<<dim3(8, MAXTILES), 256, 0, stream>>>(xbf, w1T, b1, tileExpert, tileRowBase,
                                                      rowTok, hbuf);
  gemm2_kernel<<<dim3(8, MAXTILES), 256, 0, stream>>>(hbuf, w2T, b2, tileExpert, tileRowBase,
                                                      ybuf);
  combine_kernel<<<NTOK / 4, 256, 0, stream>>>(ybuf, topRow, topW, out);
}

// Round 5
// 330.434 us; speedup vs baseline: 2.8846x; 1.0295x over previous
//
#include <hip/hip_runtime.h>
#include <math.h>
#include <stdint.h>

// MoE: B=8192 tokens, D_IN=1024, 8 experts, D_EXP=1024, top-2.
// Pipeline: one fused prep kernel (w-transpose + x-cast + fp64 gating + init)
// -> single-block slot assign -> per-expert gathered bf16 MFMA GEMMs
// (XOR-swizzled LDS, XCD-friendly grid) -> weighted combine.

#define NTOK   8192
#define DIN    1024
#define NEXP   8
#define DEXP   1024
#define MAXROWS 17408   // 16384 assignments + per-expert pad to 128 (= 17*1024)
#define MAXTILES 136

typedef __bf16 bf16x8_t __attribute__((ext_vector_type(8)));
typedef float f32x4 __attribute__((ext_vector_type(4)));

__device__ __forceinline__ unsigned short f2bf(float f) {
  union { float f; unsigned int u; } v; v.f = f;
  unsigned int u = v.u;
  u += 0x7fffu + ((u >> 16) & 1u);   // round-to-nearest-even
  return (unsigned short)(u >> 16);
}

__device__ __forceinline__ float bf2f(unsigned short s) {
  union { unsigned int u; float f; } v; v.u = ((unsigned int)s) << 16;
  return v.f;
}

__device__ __forceinline__ void async16(const void* g, void* l) {
  __builtin_amdgcn_global_load_lds((const __attribute__((address_space(1))) void*)g,
                                   (__attribute__((address_space(3))) void*)l, 16, 0, 0);
}

// fast GELU: tanh form via sigmoid, max abs err ~3e-4 (threshold is 5.7e-2)
__device__ __forceinline__ float gelu_fast(float v) {
  float u = v * (1.5957691216057308f + 0.07135481627f * v * v);
  return v * (1.0f / (1.0f + __expf(-u)));
}

// ---------------- fused prep: [0,4096) w-transpose | [4096,6144) x-cast+gate | [6144,6161) rowTok init
__global__ __launch_bounds__(256) void prep_kernel(const float* __restrict__ x,
                                                   const float* __restrict__ gw,
                                                   const float* __restrict__ w1,
                                                   const float* __restrict__ w2,
                                                   unsigned short* __restrict__ xbf,
                                                   unsigned short* __restrict__ w1T,
                                                   unsigned short* __restrict__ w2T,
                                                   float* __restrict__ outGate,
                                                   int* __restrict__ topE,
                                                   float* __restrict__ topW,
                                                   int* __restrict__ rowTok) {
  __shared__ float tile[64][68];
  int b = blockIdx.x;
  int tid = threadIdx.x;
  if (b < 4096) {
    // ---- weight transpose+cast: [e][k][n] fp32 -> [e][n][k] bf16, 64x64 tile
    int z = b >> 8;                        // 0..15
    const float* src = (z < 8) ? w1 : w2;
    unsigned short* dst = (z < 8) ? w1T : w2T;
    int e = z & 7;
    int idx = b & 255, kt = idx >> 4, nt = idx & 15;
    const float* s = src + (size_t)e * DIN * DEXP + (size_t)kt * 64 * 1024 + nt * 64;
    unsigned short* d = dst + (size_t)e * DIN * DEXP + (size_t)nt * 64 * 1024 + kt * 64;
    int c4 = (tid & 15) * 4, r0 = tid >> 4;
    #pragma unroll
    for (int p = 0; p < 4; ++p) {
      int r = r0 + p * 16;
      *(float4*)&tile[r][c4] = *(const float4*)(s + (size_t)r * 1024 + c4);
    }
    __syncthreads();
    #pragma unroll
    for (int p = 0; p < 4; ++p) {
      int nr = r0 + p * 16;
      ushort4 o;
      o.x = f2bf(tile[c4 + 0][nr]);
      o.y = f2bf(tile[c4 + 1][nr]);
      o.z = f2bf(tile[c4 + 2][nr]);
      o.w = f2bf(tile[c4 + 3][nr]);
      *(ushort4*)(d + (size_t)nr * 1024 + c4) = o;
    }
  } else if (b < 6144) {
    // ---- x fp32->bf16 + fp64 gating (one wave per token)
    int lane = tid & 63, wv = tid >> 6;
    int t = (b - 4096) * 4 + wv;
    const float4* xr = (const float4*)(x + (size_t)t * 1024);
    ushort4* xo = (ushort4*)(xbf + (size_t)t * 1024);
    double acc[NEXP];
    #pragma unroll
    for (int e = 0; e < NEXP; ++e) acc[e] = 0.0;
    #pragma unroll
    for (int j = 0; j < 4; ++j) {
      int q = lane + 64 * j;
      float4 v = xr[q];
      ushort4 r;
      r.x = f2bf(v.x); r.y = f2bf(v.y); r.z = f2bf(v.z); r.w = f2bf(v.w);
      xo[q] = r;
      float vv[4] = {v.x, v.y, v.z, v.w};
      #pragma unroll
      for (int m = 0; m < 4; ++m) {
        int k = q * 4 + m;
        float4 g0 = *(const float4*)(gw + k * 8);
        float4 g1 = *(const float4*)(gw + k * 8 + 4);
        double xv = (double)vv[m];
        acc[0] += xv * (double)g0.x; acc[1] += xv * (double)g0.y;
        acc[2] += xv * (double)g0.z; acc[3] += xv * (double)g0.w;
        acc[4] += xv * (double)g1.x; acc[5] += xv * (double)g1.y;
        acc[6] += xv * (double)g1.z; acc[7] += xv * (double)g1.w;
      }
    }
    #pragma unroll
    for (int off = 32; off > 0; off >>= 1) {
      #pragma unroll
      for (int e = 0; e < NEXP; ++e) acc[e] += __shfl_xor(acc[e], off);
    }
    if (lane == 0) {
      int e0 = 0; double v0 = acc[0];
      #pragma unroll
      for (int e = 1; e < NEXP; ++e) if (acc[e] > v0) { v0 = acc[e]; e0 = e; }
      int e1 = -1; double v1 = -1e300;
      #pragma unroll
      for (int e = 0; e < NEXP; ++e) if (e != e0 && acc[e] > v1) { v1 = acc[e]; e1 = e; }
      float ex = expf((float)(v1 - v0));
      float inv = 1.0f / (1.0f + ex);
      float w0 = inv, w1v = ex * inv;
      float g8[8];
      #pragma unroll
      for (int e = 0; e < NEXP; ++e) g8[e] = 0.f;
      g8[e0] = w0; g8[e1] = w1v;
      float4* gp = (float4*)(outGate + t * 8);
      gp[0] = *(float4*)&g8[0];
      gp[1] = *(float4*)&g8[4];
      topE[t * 2 + 0] = e0; topE[t * 2 + 1] = e1;
      topW[t * 2 + 0] = w0; topW[t * 2 + 1] = w1v;
    }
  } else {
    // ---- rowTok = -1 (17 blocks x 1024 ints)
    int base = (b - 6144) * 1024 + tid * 4;
    int4 m1 = make_int4(-1, -1, -1, -1);
    *(int4*)(rowTok + base) = m1;
  }
}

// ---------------- slots, tile table, topRow, rowTok scatter: one block ----------------
__global__ __launch_bounds__(1024) void slot_kernel(const int* __restrict__ topE,
                                                    int* __restrict__ topRow,
                                                    int* __restrict__ rowTok,
                                                    int* __restrict__ tileExpert,
                                                    int* __restrict__ tileRowBase) {
  __shared__ int wtot[16][NEXP];
  __shared__ int wbase[16][NEXP];
  __shared__ int soff[NEXP];
  int tid = threadIdx.x, lane = tid & 63, wv = tid >> 6;
  int a0 = tid * 16;
  unsigned long long pk = 0ull;
  int cnt[NEXP];
  #pragma unroll
  for (int e = 0; e < NEXP; ++e) cnt[e] = 0;
  for (int i = 0; i < 16; ++i) {
    int e = topE[a0 + i];
    pk |= (unsigned long long)e << (i * 4);
    cnt[e]++;
  }
  int excl[NEXP];
  #pragma unroll
  for (int e = 0; e < NEXP; ++e) {
    int v = cnt[e], sum = v;
    #pragma unroll
    for (int d = 1; d < 64; d <<= 1) {
      int u = __shfl_up(sum, d);
      if (lane >= d) sum += u;
    }
    excl[e] = sum - v;
    if (lane == 63) wtot[wv][e] = sum;
  }
  __syncthreads();
  if (tid == 0) {
    int counts[NEXP];
    for (int e = 0; e < NEXP; ++e) {
      int s = 0;
      for (int w = 0; w < 16; ++w) { wbase[w][e] = s; s += wtot[w][e]; }
      counts[e] = s;
    }
    int row = 0, tile = 0;
    for (int e = 0; e < NEXP; ++e) {
      soff[e] = row;
      int nt = (counts[e] + 127) >> 7;
      for (int i = 0; i < nt; ++i) { tileExpert[tile] = e; tileRowBase[tile] = row + i * 128; ++tile; }
      row += nt << 7;
    }
    for (; tile < MAXTILES; ++tile) tileExpert[tile] = -1;
  }
  __syncthreads();
  int base[NEXP], run[NEXP];
  #pragma unroll
  for (int e = 0; e < NEXP; ++e) { base[e] = soff[e] + wbase[wv][e] + excl[e]; run[e] = 0; }
  for (int i = 0; i < 16; ++i) {
    int e = (int)((pk >> (i * 4)) & 7ull);
    int row = base[e] + run[e]++;
    rowTok[row] = (a0 + i) >> 1;
    topRow[a0 + i] = row;
  }
}

// ---------------- GEMM1: h = gelu(Xg @ W1[e] + b1[e]), bf16 out ----------------
// grid (MAXTILES, 8): blocks sharing a tile (same A) are 136 apart in linear
// order -> same XCD under round-robin -> A-tile fetched into one L2.
__global__ __launch_bounds__(256) void gemm1_kernel(const unsigned short* __restrict__ xbf,
                                                    const unsigned short* __restrict__ w1T,
                                                    const float* __restrict__ b1,
                                                    const int* __restrict__ tileExpert,
                                                    const int* __restrict__ tileRowBase,
                                                    const int* __restrict__ rowTok,
                                                    unsigned short* __restrict__ h) {
  int tileId = blockIdx.x;
  int e = tileExpert[tileId];
  if (e < 0) return;
  int rowBase = tileRowBase[tileId];
  int n0 = blockIdx.y * 128;
  __shared__ __align__(16) unsigned short sm[128 * 64 * 2];  // 32KB: sA | sB
  unsigned short* sA = sm;
  unsigned short* sB = sm + 128 * 64;
  int tid = threadIdx.x, lane = tid & 63, wv = tid >> 6;
  int srow = tid >> 3;                       // 0..31 (+32 per issue)
  int scolSw = (((tid & 7) ^ ((tid >> 3) & 7)) * 8);   // swizzled k-chunk fetch
  int tok[4];
  #pragma unroll
  for (int i = 0; i < 4; ++i) {
    int tk = rowTok[rowBase + srow + i * 32];
    tok[i] = tk < 0 ? 0 : tk;
  }
  const unsigned short* Bmat = w1T + (size_t)e * DIN * DEXP;
  int wm = ((tid >> 6) & 1) * 64, wn = (tid >> 7) * 64;
  int rsel = lane & 15, q = lane >> 4;
  int rk = rsel & 7;
  f32x4 acc[4][4] = {};
  for (int kk = 0; kk < DIN; kk += 64) {
    #pragma unroll
    for (int i = 0; i < 4; ++i) {
      int abase = __builtin_amdgcn_readfirstlane((wv * 8 + i * 32) * 128);
      async16(xbf + (size_t)tok[i] * 1024 + kk + scolSw, (char*)sm + abase);
      async16(Bmat + (size_t)(n0 + srow + i * 32) * 1024 + kk + scolSw,
              (char*)sm + abase + 16384);
    }
    __syncthreads();
    #pragma unroll
    for (int ks = 0; ks < 64; ks += 32) {
      int co = (((ks >> 3) + q) ^ rk) * 8;   // swizzled element offset in row
      bf16x8_t af[4], bfr[4];
      #pragma unroll
      for (int mi = 0; mi < 4; ++mi)
        af[mi] = *(const bf16x8_t*)&sA[(wm + mi * 16 + rsel) * 64 + co];
      #pragma unroll
      for (int ni = 0; ni < 4; ++ni)
        bfr[ni] = *(const bf16x8_t*)&sB[(wn + ni * 16 + rsel) * 64 + co];
      #pragma unroll
      for (int mi = 0; mi < 4; ++mi)
        #pragma unroll
        for (int ni = 0; ni < 4; ++ni)
          acc[mi][ni] = __builtin_amdgcn_mfma_f32_16x16x32_bf16(af[mi], bfr[ni], acc[mi][ni], 0, 0, 0);
    }
    __syncthreads();
  }
  float b1v[4];
  int quad = lane >> 4;
  #pragma unroll
  for (int ni = 0; ni < 4; ++ni) b1v[ni] = b1[e * 1024 + n0 + wn + ni * 16 + rsel];
  #pragma unroll
  for (int mi = 0; mi < 4; ++mi)
    #pragma unroll
    for (int ni = 0; ni < 4; ++ni)
      #pragma unroll
      for (int r = 0; r < 4; ++r) {
        int m = wm + mi * 16 + quad * 4 + r;
        int n = wn + ni * 16 + rsel;
        sm[m * 128 + n] = f2bf(gelu_fast(acc[mi][ni][r] + b1v[ni]));
      }
  __syncthreads();
  #pragma unroll
  for (int i = 0; i < 8; ++i) {
    int idx = i * 2048 + tid * 8;
    int m = idx >> 7, c = idx & 127;
    int g = rowBase + m;
    *(uint4*)(h + (size_t)g * 1024 + n0 + c) = *(const uint4*)&sm[idx];
  }
}

// ---------------- GEMM2: y[row] = h[row] @ W2[e] + b2[e] (bf16) ----------------
__global__ __launch_bounds__(256) void gemm2_kernel(const unsigned short* __restrict__ h,
                                                    const unsigned short* __restrict__ w2T,
                                                    const float* __restrict__ b2,
                                                    const int* __restrict__ tileExpert,
                                                    const int* __restrict__ tileRowBase,
                                                    unsigned short* __restrict__ y) {
  int tileId = blockIdx.x;
  int e = tileExpert[tileId];
  if (e < 0) return;
  int rowBase = tileRowBase[tileId];
  int n0 = blockIdx.y * 128;
  __shared__ __align__(16) unsigned short sm[128 * 64 * 2];
  unsigned short* sA = sm;
  unsigned short* sB = sm + 128 * 64;
  int tid = threadIdx.x, lane = tid & 63, wv = tid >> 6;
  int srow = tid >> 3;
  int scolSw = (((tid & 7) ^ ((tid >> 3) & 7)) * 8);
  const unsigned short* Bmat = w2T + (size_t)e * DEXP * DEXP;
  int wm = ((tid >> 6) & 1) * 64, wn = (tid >> 7) * 64;
  int rsel = lane & 15, q = lane >> 4;
  int rk = rsel & 7;
  f32x4 acc[4][4] = {};
  for (int kk = 0; kk < DEXP; kk += 64) {
    #pragma unroll
    for (int i = 0; i < 4; ++i) {
      int abase = __builtin_amdgcn_readfirstlane((wv * 8 + i * 32) * 128);
      async16(h + (size_t)(rowBase + srow + i * 32) * 1024 + kk + scolSw, (char*)sm + abase);
      async16(Bmat + (size_t)(n0 + srow + i * 32) * 1024 + kk + scolSw,
              (char*)sm + abase + 16384);
    }
    __syncthreads();
    #pragma unroll
    for (int ks = 0; ks < 64; ks += 32) {
      int co = (((ks >> 3) + q) ^ rk) * 8;
      bf16x8_t af[4], bfr[4];
      #pragma unroll
      for (int mi = 0; mi < 4; ++mi)
        af[mi] = *(const bf16x8_t*)&sA[(wm + mi * 16 + rsel) * 64 + co];
      #pragma unroll
      for (int ni = 0; ni < 4; ++ni)
        bfr[ni] = *(const bf16x8_t*)&sB[(wn + ni * 16 + rsel) * 64 + co];
      #pragma unroll
      for (int mi = 0; mi < 4; ++mi)
        #pragma unroll
        for (int ni = 0; ni < 4; ++ni)
          acc[mi][ni] = __builtin_amdgcn_mfma_f32_16x16x32_bf16(af[mi], bfr[ni], acc[mi][ni], 0, 0, 0);
    }
    __syncthreads();
  }
  float b2v[4];
  int quad = lane >> 4;
  #pragma unroll
  for (int ni = 0; ni < 4; ++ni) b2v[ni] = b2[e * 1024 + n0 + wn + ni * 16 + rsel];
  #pragma unroll
  for (int mi = 0; mi < 4; ++mi)
    #pragma unroll
    for (int ni = 0; ni < 4; ++ni)
      #pragma unroll
      for (int r = 0; r < 4; ++r) {
        int m = wm + mi * 16 + quad * 4 + r;
        int n = wn + ni * 16 + rsel;
        sm[m * 128 + n] = f2bf(acc[mi][ni][r] + b2v[ni]);
      }
  __syncthreads();
  #pragma unroll
  for (int i = 0; i < 8; ++i) {
    int idx = i * 2048 + tid * 8;
    int m = idx >> 7, c = idx & 127;
    int g = rowBase + m;
    *(uint4*)(y + (size_t)g * 1024 + n0 + c) = *(const uint4*)&sm[idx];
  }
}

// ---------------- combine: out[t] = w0*y[r0] + w1*y[r1] ----------------
__global__ __launch_bounds__(256) void combine_kernel(const unsigned short* __restrict__ y,
                                                      const int* __restrict__ topRow,
                                                      const float* __restrict__ topW,
                                                      float* __restrict__ out) {
  int tid = threadIdx.x;
  int wv = tid >> 6, lane = tid & 63;
  int t = blockIdx.x * 4 + wv;
  int r0 = topRow[t * 2 + 0], r1 = topRow[t * 2 + 1];
  float w0 = topW[t * 2 + 0], w1 = topW[t * 2 + 1];
  const unsigned short* p0 = y + (size_t)r0 * 1024 + lane * 16;
  const unsigned short* p1 = y + (size_t)r1 * 1024 + lane * 16;
  float* op = out + (size_t)t * 1024 + lane * 16;
  #pragma unroll
  for (int hh = 0; hh < 2; ++hh) {
    union { uint4 v; unsigned short s[8]; } a, b;
    a.v = *(const uint4*)(p0 + hh * 8);
    b.v = *(const uint4*)(p1 + hh * 8);
    float o[8];
    #pragma unroll
    for (int j = 0; j < 8; ++j)
      o[j] = w0 * bf2f(a.s[j]) + w1 * bf2f(b.s[j]);
    *(float4*)(op + hh * 8) = *(float4*)&o[0];
    *(float4*)(op + hh * 8 + 4) = *(float4*)&o[4];
  }
}

extern "C" void kernel_launch(void* const* d_in, const int* in_sizes, int n_in,
                              void* d_out, int out_size, void* d_ws, size_t ws_size,
                              hipStream_t stream) {
  const float* x  = (const float*)d_in[0];
  const float* gw = (const float*)d_in[1];
  const float* w1 = (const float*)d_in[2];
  const float* b1 = (const float*)d_in[3];
  const float* w2 = (const float*)d_in[4];
  const float* b2 = (const float*)d_in[5];
  float* out = (float*)d_out;

  char* ws = (char*)d_ws;
  int* tileExpert  = (int*)ws;                            // 136
  int* tileRowBase = tileExpert + MAXTILES;               // 136
  int* topE        = tileRowBase + MAXTILES;              // 16384
  int* topRow      = topE + 16384;                        // 16384
  float* topW      = (float*)(topRow + 16384);            // 16384
  int* rowTok      = (int*)(ws + (256 << 10));            // 17408 (16B aligned)
  unsigned short* xbf  = (unsigned short*)(ws + (512 << 10));
  unsigned short* w1T  = xbf + (size_t)NTOK * DIN;
  unsigned short* w2T  = w1T + (size_t)NEXP * DIN * DEXP;
  unsigned short* hbuf = w2T + (size_t)NEXP * DEXP * DEXP;
  unsigned short* ybuf = hbuf + (size_t)MAXROWS * DEXP;

  prep_kernel<<<4096 + 2048 + 17, 256, 0, stream>>>(x, gw, w1, w2, xbf, w1T, w2T,
                                                    out + (size_t)NTOK * DEXP,
                                                    topE, topW, rowTok);
  slot_kernel<<<1, 1024, 0, stream>>>(topE, topRow, rowTok, tileExpert, tileRowBase);
  gemm1_kernel<<<dim3(MAXTILES, 8), 256, 0, stream>>>(xbf, w1T, b1, tileExpert, tileRowBase,
                                                      rowTok, hbuf);
  gemm2_kernel<<<dim3(MAXTILES, 8), 256, 0, stream>>>(hbuf, w2T, b2, tileExpert, tileRowBase,
                                                      ybuf);
  combine_kernel<<<NTOK / 4, 256, 0, stream>>>(ybuf, topRow, topW, out);
}